// Round 7
// baseline (420.221 us; speedup 1.0000x reference)
//
#include <hip/hip_runtime.h>
#include <hip/hip_bf16.h>
#include <math.h>

#define N_NODES 100000
#define DIM 128
#define NH 8
#define NC 16
#define E_EDGES 400000
#define LN_EPS 1e-3f
#define SCAN_B 1024

typedef __attribute__((ext_vector_type(8))) short short8v;
typedef __attribute__((ext_vector_type(4))) float float4v;

__device__ __forceinline__ short bf16bits(float v) {
    __hip_bfloat16 b = __float2bfloat16(v);
    return *(short*)&b;
}

// ---------------- fused transposed weights (bf16) + fused biases -------------
// Wt[c][d], c in [0,768): sections of 128 cols:
//  0: Wk·BD(Watt0)·prior0/sqrt(C)   1: Wk·BD(Watt1)·prior1/sqrt(C)
//  2: Wm·BD(Wmsg0)                  3: Wm·BD(Wmsg1)
//  4: Wq                            5: Wa
__global__ __launch_bounds__(128) void fuse_weights(
    const float* __restrict__ Wk, const float* __restrict__ bk,
    const float* __restrict__ Wm, const float* __restrict__ bm,
    const float* __restrict__ Wq, const float* __restrict__ bq,
    const float* __restrict__ Wa, const float* __restrict__ ba,
    const float* __restrict__ Watt0, const float* __restrict__ Wmsg0,
    const float* __restrict__ Watt1, const float* __restrict__ Wmsg1,
    const float* __restrict__ prior0, const float* __restrict__ prior1,
    __hip_bfloat16* __restrict__ Wt, float* __restrict__ bias)
{
    const int c = blockIdx.x;        // 0..767
    const int d = threadIdx.x;       // 0..127
    const int sec = c >> 7, j = c & 127, h = j >> 4, l = j & 15;
    float v, b;
    if (sec == 4)      { v = Wq[d * DIM + j]; b = bq[j]; }
    else if (sec == 5) { v = Wa[d * DIM + j]; b = ba[j]; }
    else {
        const float* W1 = (sec < 2) ? Wk : Wm;
        const float* bs = (sec < 2) ? bk : bm;
        const float* W2 = (sec == 0) ? Watt0 : (sec == 1) ? Watt1
                          : (sec == 2) ? Wmsg0 : Wmsg1;
        float scale = (sec == 0) ? prior0[h] * 0.25f
                    : (sec == 1) ? prior1[h] * 0.25f : 1.f;
        float s = 0.f, sb = 0.f;
        #pragma unroll
        for (int kk = 0; kk < NC; ++kk) {
            float w2 = W2[h * 256 + kk * 16 + l];
            s  = fmaf(W1[d * DIM + h * 16 + kk], w2, s);
            sb = fmaf(bs[h * 16 + kk], w2, sb);
        }
        v = s * scale; b = sb * scale;
    }
    Wt[(size_t)c * DIM + d] = __float2bfloat16(v);
    if (d == 0) bias[c] = b;
}

// ---------------- proj: bf16 MFMA GEMM [N,128]@[128,640] ---------------------
// Block = 256 threads (4 waves), 32 rows. Wave w owns the contiguous 32-col
// stripe [w*32, w*32+32) of each of the 5 sections; it transposes its MFMA
// fragments through a PRIVATE padded LDS tile (same-wave DS ordering, so NO
// __syncthreads anywhere), then stores 16B chunks; 4 waves jointly cover each
// 256B output row, keeping writes full-line.
__global__ __launch_bounds__(256) void proj_mfma(
    const float* __restrict__ x,             // [N][128] fp32
    const __hip_bfloat16* __restrict__ Wt,   // [768][128]
    const float* __restrict__ bias,          // [768]
    __hip_bfloat16* __restrict__ kattC,      // [2N][128]
    __hip_bfloat16* __restrict__ mmsgC,      // [2N][128]
    __hip_bfloat16* __restrict__ qb)         // [N][128]
{
    __shared__ short tile[4][32][40];        // pad 32->40 (16B-aligned rows)
    const int wave = threadIdx.x >> 6, lane = threadIdx.x & 63;
    const int quad = lane >> 4, mcol = lane & 15;
    const int r0 = blockIdx.x * 32;

    // A fragments: fp32 rows -> bf16, explicit float4 loads
    short8v a0[4], a1[4];
    {
        const float4* xp0 = (const float4*)(x + (size_t)(r0 + mcol) * DIM + quad * 8);
        const float4* xp1 = (const float4*)(x + (size_t)(r0 + 16 + mcol) * DIM + quad * 8);
        #pragma unroll
        for (int kb = 0; kb < 4; ++kb) {
            float4 u0 = xp0[kb * 8], v0 = xp0[kb * 8 + 1];
            float4 u1 = xp1[kb * 8], v1 = xp1[kb * 8 + 1];
            a0[kb][0] = bf16bits(u0.x); a0[kb][1] = bf16bits(u0.y);
            a0[kb][2] = bf16bits(u0.z); a0[kb][3] = bf16bits(u0.w);
            a0[kb][4] = bf16bits(v0.x); a0[kb][5] = bf16bits(v0.y);
            a0[kb][6] = bf16bits(v0.z); a0[kb][7] = bf16bits(v0.w);
            a1[kb][0] = bf16bits(u1.x); a1[kb][1] = bf16bits(u1.y);
            a1[kb][2] = bf16bits(u1.z); a1[kb][3] = bf16bits(u1.w);
            a1[kb][4] = bf16bits(v1.x); a1[kb][5] = bf16bits(v1.y);
            a1[kb][6] = bf16bits(v1.z); a1[kb][7] = bf16bits(v1.w);
        }
    }

    const int srow = lane >> 2;          // 0..15
    const int scol = (lane & 3) * 8;     // 0,8,16,24 (shorts)

    #pragma unroll
    for (int s = 0; s < 5; ++s) {
        #pragma unroll
        for (int tp = 0; tp < 2; ++tp) {
            const int c0 = s * 128 + wave * 32 + tp * 16;
            const short* wp = (const short*)Wt + (size_t)(c0 + mcol) * DIM + quad * 8;
            float4v acc0 = {0.f, 0.f, 0.f, 0.f};
            float4v acc1 = {0.f, 0.f, 0.f, 0.f};
            #pragma unroll
            for (int kb = 0; kb < 4; ++kb) {
                short8v bfr = *(const short8v*)(wp + kb * 32);
                acc0 = __builtin_amdgcn_mfma_f32_16x16x32_bf16(a0[kb], bfr, acc0, 0, 0, 0);
                acc1 = __builtin_amdgcn_mfma_f32_16x16x32_bf16(a1[kb], bfr, acc1, 0, 0, 0);
            }
            const float bcol = bias[c0 + mcol];
            const int cc = tp * 16 + mcol, rq = quad * 4;
            #pragma unroll
            for (int g = 0; g < 4; ++g) {
                tile[wave][rq + g][cc]      = bf16bits(acc0[g] + bcol);
                tile[wave][rq + 16 + g][cc] = bf16bits(acc1[g] + bcol);
            }
        }
        __hip_bfloat16* dst =
            (s == 0) ? kattC + (size_t)r0 * DIM :
            (s == 1) ? kattC + ((size_t)N_NODES + r0) * DIM :
            (s == 2) ? mmsgC + (size_t)r0 * DIM :
            (s == 3) ? mmsgC + ((size_t)N_NODES + r0) * DIM :
                       qb    + (size_t)r0 * DIM;
        #pragma unroll
        for (int it = 0; it < 2; ++it) {
            int row = it * 16 + srow;
            short8v vdat = *(short8v*)&tile[wave][row][scol];
            *(short8v*)((short*)dst + (size_t)row * DIM + wave * 32 + scol) = vdat;
        }
    }
}

// ---------------- CSR build ----------------
__global__ __launch_bounds__(256) void hist_kernel(
    const int* __restrict__ dst0, const int* __restrict__ dst1,
    int* __restrict__ counts)
{
    int e = blockIdx.x * 256 + threadIdx.x;
    if (e < E_EDGES) atomicAdd(&counts[dst0[e]], 1);
    int e1 = e - E_EDGES;
    if (e1 >= 0 && e1 < E_EDGES) atomicAdd(&counts[dst1[e1]], 1);
}

__global__ __launch_bounds__(SCAN_B) void scanA_kernel(
    const int* __restrict__ counts, int* __restrict__ row_ptr,
    int* __restrict__ bsum)
{
    __shared__ int buf[2][SCAN_B];
    int i = blockIdx.x * SCAN_B + threadIdx.x;
    int v = (i < N_NODES) ? counts[i] : 0;
    int cur = 0;
    buf[0][threadIdx.x] = v;
    __syncthreads();
    #pragma unroll
    for (int off = 1; off < SCAN_B; off <<= 1) {
        int t = buf[cur][threadIdx.x];
        int add = (threadIdx.x >= off) ? buf[cur][threadIdx.x - off] : 0;
        buf[cur ^ 1][threadIdx.x] = t + add;
        cur ^= 1;
        __syncthreads();
    }
    int inc = buf[cur][threadIdx.x];
    if (i < N_NODES) row_ptr[i] = inc - v;           // block-local exclusive
    if (threadIdx.x == SCAN_B - 1) bsum[blockIdx.x] = inc;
}

// parallel exclusive scan of the (<=128) block sums, single block
__global__ __launch_bounds__(128) void scanB_kernel(int* __restrict__ bsum, int nblocks)
{
    __shared__ int buf[2][128];
    int t = threadIdx.x;
    int v = (t < nblocks) ? bsum[t] : 0;
    buf[0][t] = v;
    __syncthreads();
    int cur = 0;
    #pragma unroll
    for (int off = 1; off < 128; off <<= 1) {
        int a = buf[cur][t];
        if (t >= off) a += buf[cur][t - off];
        buf[cur ^ 1][t] = a;
        cur ^= 1;
        __syncthreads();
    }
    if (t < nblocks) bsum[t] = buf[cur][t] - v;   // exclusive
}

// scatter fuses the former scanC: pos = local_excl(atomic) + bsum[block].
// Afterwards row_ptr[n] = local_excl(n)+cnt(n); consumers reconstruct start.
__global__ __launch_bounds__(256) void scatter_kernel(
    const int* __restrict__ src0, const int* __restrict__ dst0,
    const int* __restrict__ src1, const int* __restrict__ dst1,
    int* __restrict__ row_ptr, const int* __restrict__ bsum,
    unsigned int* __restrict__ eidx)
{
    int e = blockIdx.x * 256 + threadIdx.x;
    if (e < E_EDGES) {
        int d = dst0[e];
        int pos = atomicAdd(&row_ptr[d], 1) + bsum[d >> 10];
        eidx[pos] = (unsigned int)src0[e];
    }
    int e1 = e - E_EDGES;
    if (e1 >= 0 && e1 < E_EDGES) {
        int d = dst1[e1];
        int pos = atomicAdd(&row_ptr[d], 1) + bsum[d >> 10];
        eidx[pos] = (unsigned int)(src1[e1] + N_NODES);
    }
}

// ---------------- aggregation: one wave per node, no atomics -----------------
// Lane owns channel pair (2*lane, 2*lane+1). Writes gelu(pooled/denom) in bf16.
__global__ __launch_bounds__(256) void agg_kernel(
    const __hip_bfloat162* __restrict__ katt,   // [2N][64] channel pairs
    const __hip_bfloat162* __restrict__ mmsg,   // [2N][64]
    const __hip_bfloat162* __restrict__ qb2,    // [N][64]
    const int* __restrict__ row_ptr, const int* __restrict__ counts,
    const int* __restrict__ bsum,
    const unsigned int* __restrict__ eidx,
    __hip_bfloat162* __restrict__ pooled2)      // [N][64]
{
    const int wave = threadIdx.x >> 6, lane = threadIdx.x & 63;
    const int n = blockIdx.x * 4 + wave;
    if (n >= N_NODES) return;
    const int cnt = counts[n];
    const int start = row_ptr[n] + bsum[n >> 10] - cnt;
    __hip_bfloat162 qv = qb2[(size_t)n * 64 + lane];
    const float qx = __bfloat162float(qv.x), qy = __bfloat162float(qv.y);

    float accx = 0.f, accy = 0.f, den = 0.f;
    int i = 0;
    for (; i + 4 <= cnt; i += 4) {
        unsigned int r0 = eidx[start + i];
        unsigned int r1 = eidx[start + i + 1];
        unsigned int r2 = eidx[start + i + 2];
        unsigned int r3 = eidx[start + i + 3];
        __hip_bfloat162 ka0 = katt[(size_t)r0 * 64 + lane];
        __hip_bfloat162 ka1 = katt[(size_t)r1 * 64 + lane];
        __hip_bfloat162 ka2 = katt[(size_t)r2 * 64 + lane];
        __hip_bfloat162 ka3 = katt[(size_t)r3 * 64 + lane];
        __hip_bfloat162 mg0 = mmsg[(size_t)r0 * 64 + lane];
        __hip_bfloat162 mg1 = mmsg[(size_t)r1 * 64 + lane];
        __hip_bfloat162 mg2 = mmsg[(size_t)r2 * 64 + lane];
        __hip_bfloat162 mg3 = mmsg[(size_t)r3 * 64 + lane];
        float p0 = fmaf(__bfloat162float(ka0.x), qx, __bfloat162float(ka0.y) * qy);
        float p1 = fmaf(__bfloat162float(ka1.x), qx, __bfloat162float(ka1.y) * qy);
        float p2 = fmaf(__bfloat162float(ka2.x), qx, __bfloat162float(ka2.y) * qy);
        float p3 = fmaf(__bfloat162float(ka3.x), qx, __bfloat162float(ka3.y) * qy);
        p0 += __shfl_xor(p0, 1, 64); p0 += __shfl_xor(p0, 2, 64); p0 += __shfl_xor(p0, 4, 64);
        p1 += __shfl_xor(p1, 1, 64); p1 += __shfl_xor(p1, 2, 64); p1 += __shfl_xor(p1, 4, 64);
        p2 += __shfl_xor(p2, 1, 64); p2 += __shfl_xor(p2, 2, 64); p2 += __shfl_xor(p2, 4, 64);
        p3 += __shfl_xor(p3, 1, 64); p3 += __shfl_xor(p3, 2, 64); p3 += __shfl_xor(p3, 4, 64);
        float e0 = __expf(p0), e1 = __expf(p1), e2 = __expf(p2), e3 = __expf(p3);
        accx = fmaf(e0, __bfloat162float(mg0.x), accx);
        accy = fmaf(e0, __bfloat162float(mg0.y), accy);
        accx = fmaf(e1, __bfloat162float(mg1.x), accx);
        accy = fmaf(e1, __bfloat162float(mg1.y), accy);
        accx = fmaf(e2, __bfloat162float(mg2.x), accx);
        accy = fmaf(e2, __bfloat162float(mg2.y), accy);
        accx = fmaf(e3, __bfloat162float(mg3.x), accx);
        accy = fmaf(e3, __bfloat162float(mg3.y), accy);
        den += (e0 + e1) + (e2 + e3);
    }
    for (; i < cnt; ++i) {
        unsigned int r0 = eidx[start + i];
        __hip_bfloat162 ka0 = katt[(size_t)r0 * 64 + lane];
        __hip_bfloat162 mg0 = mmsg[(size_t)r0 * 64 + lane];
        float p0 = fmaf(__bfloat162float(ka0.x), qx, __bfloat162float(ka0.y) * qy);
        p0 += __shfl_xor(p0, 1, 64); p0 += __shfl_xor(p0, 2, 64); p0 += __shfl_xor(p0, 4, 64);
        float e0 = __expf(p0);
        accx = fmaf(e0, __bfloat162float(mg0.x), accx);
        accy = fmaf(e0, __bfloat162float(mg0.y), accy);
        den += e0;
    }

    float vx = 0.f, vy = 0.f;
    if (den > 0.f) { vx = accx / den; vy = accy / den; }
    vx = 0.5f * vx * (1.f + erff(vx * 0.70710678118654752f));
    vy = 0.5f * vy * (1.f + erff(vy * 0.70710678118654752f));
    __hip_bfloat162 o; o.x = __float2bfloat16(vx); o.y = __float2bfloat16(vy);
    pooled2[(size_t)n * 64 + lane] = o;
}

// ---------------- final: MFMA GEMM(Wa) -> skip -> LayerNorm ------------------
__global__ __launch_bounds__(256) void final_mfma(
    const __hip_bfloat16* __restrict__ pooled,  // [N][128] bf16, gelu applied
    const __hip_bfloat16* __restrict__ Wt,      // [768][128]; rows 640.. = Wa^T
    const float* __restrict__ bias,             // [768]; 640.. = ba
    const float* __restrict__ x,
    const float* __restrict__ skip, const float* __restrict__ gamma,
    const float* __restrict__ beta, float* __restrict__ out)
{
    __shared__ float hs[32][DIM];
    const int wave = threadIdx.x >> 6, lane = threadIdx.x & 63;
    const int quad = lane >> 4, mcol = lane & 15;
    const int r0 = blockIdx.x * 32;

    short8v a0[4], a1[4];
    const short* pp0 = (const short*)pooled + (size_t)(r0 + mcol) * DIM + quad * 8;
    const short* pp1 = pp0 + 16 * DIM;
    #pragma unroll
    for (int kb = 0; kb < 4; ++kb) {
        a0[kb] = *(const short8v*)(pp0 + kb * 32);
        a1[kb] = *(const short8v*)(pp1 + kb * 32);
    }
    const float alpha = 1.f / (1.f + expf(-skip[0]));

    #pragma unroll
    for (int t = 0; t < 2; ++t) {
        const int c0 = wave * 32 + t * 16;
        const short* wp = (const short*)Wt + (size_t)(640 + c0 + mcol) * DIM + quad * 8;
        float4v acc0 = {0.f, 0.f, 0.f, 0.f};
        float4v acc1 = {0.f, 0.f, 0.f, 0.f};
        #pragma unroll
        for (int kb = 0; kb < 4; ++kb) {
            short8v bfr = *(const short8v*)(wp + kb * 32);
            acc0 = __builtin_amdgcn_mfma_f32_16x16x32_bf16(a0[kb], bfr, acc0, 0, 0, 0);
            acc1 = __builtin_amdgcn_mfma_f32_16x16x32_bf16(a1[kb], bfr, acc1, 0, 0, 0);
        }
        const float bcol = bias[640 + c0 + mcol];
        const int cc = c0 + mcol;
        const int rq = quad * 4;
        #pragma unroll
        for (int g = 0; g < 4; ++g) {
            int rA = rq + g, rB = rq + 16 + g;
            hs[rA][cc] = alpha * (acc0[g] + bcol)
                       + (1.f - alpha) * x[(size_t)(r0 + rA) * DIM + cc];
            hs[rB][cc] = alpha * (acc1[g] + bcol)
                       + (1.f - alpha) * x[(size_t)(r0 + rB) * DIM + cc];
        }
    }
    __syncthreads();

    float gam0 = gamma[lane], gam1 = gamma[lane + 64];
    float bet0 = beta[lane],  bet1 = beta[lane + 64];
    for (int r = wave; r < 32; r += 4) {
        int row = r0 + r;
        float v0 = hs[r][lane], v1 = hs[r][lane + 64];
        float s = v0 + v1, s2 = v0 * v0 + v1 * v1;
        #pragma unroll
        for (int off = 1; off < 64; off <<= 1) {
            s  += __shfl_xor(s,  off, 64);
            s2 += __shfl_xor(s2, off, 64);
        }
        float mu = s * (1.f / 128.f);
        float var = s2 * (1.f / 128.f) - mu * mu;
        float rstd = rsqrtf(var + LN_EPS);
        out[(size_t)row * DIM + lane]      = (v0 - mu) * rstd * gam0 + bet0;
        out[(size_t)row * DIM + lane + 64] = (v1 - mu) * rstd * gam1 + bet1;
    }
}

extern "C" void kernel_launch(void* const* d_in, const int* in_sizes, int n_in,
                              void* d_out, int out_size, void* d_ws, size_t ws_size,
                              hipStream_t stream) {
    const float* x     = (const float*)d_in[0];
    const int*   src0  = (const int*)d_in[1];
    const int*   dst0  = (const int*)d_in[2];
    const int*   src1  = (const int*)d_in[3];
    const int*   dst1  = (const int*)d_in[4];
    const float* Wk    = (const float*)d_in[5];
    const float* bk    = (const float*)d_in[6];
    const float* Wm    = (const float*)d_in[7];
    const float* bm    = (const float*)d_in[8];
    const float* Wq    = (const float*)d_in[9];
    const float* bq    = (const float*)d_in[10];
    const float* Wa    = (const float*)d_in[11];
    const float* ba    = (const float*)d_in[12];
    const float* Watt0 = (const float*)d_in[13];
    const float* Wmsg0 = (const float*)d_in[14];
    const float* Watt1 = (const float*)d_in[15];
    const float* Wmsg1 = (const float*)d_in[16];
    const float* prior0= (const float*)d_in[17];
    const float* prior1= (const float*)d_in[18];
    const float* skip  = (const float*)d_in[19];
    const float* gamma = (const float*)d_in[20];
    const float* beta  = (const float*)d_in[21];
    float* out = (float*)d_out;

    const size_t nd = (size_t)N_NODES * DIM;
    // Workspace (~158 MB):
    //   Wt [768*128 bf16] | bias [768 f32] | kattC [2nd bf16] | mmsgC [2nd bf16]
    //   | qb [nd bf16] | pooled [nd bf16] | counts/row_ptr [N i32]
    //   | bsum [128 i32] | eidx [2E u32]
    char* wsb = (char*)d_ws;
    __hip_bfloat16* Wt    = (__hip_bfloat16*)wsb;  wsb += (size_t)768 * DIM * 2;
    float* bias           = (float*)wsb;           wsb += 768 * 4;
    __hip_bfloat16* kattC = (__hip_bfloat16*)wsb;  wsb += 2 * nd * 2;
    __hip_bfloat16* mmsgC = (__hip_bfloat16*)wsb;  wsb += 2 * nd * 2;
    __hip_bfloat16* qb    = (__hip_bfloat16*)wsb;  wsb += nd * 2;
    __hip_bfloat16* pooled= (__hip_bfloat16*)wsb;  wsb += nd * 2;
    int* counts  = (int*)wsb;                      wsb += (size_t)N_NODES * 4;
    int* row_ptr = (int*)wsb;                      wsb += (size_t)N_NODES * 4;
    int* bsum    = (int*)wsb;                      wsb += 128 * 4;
    unsigned int* eidx = (unsigned int*)wsb;

    hipMemsetAsync(counts, 0, (size_t)N_NODES * 4, stream);

    const int scan_blocks = (N_NODES + SCAN_B - 1) / SCAN_B;   // 98
    const int edge_blocks = (2 * E_EDGES + 255) / 256;         // 3125

    // CSR chain (independent of projections)
    hist_kernel<<<dim3(edge_blocks), dim3(256), 0, stream>>>(dst0, dst1, counts);
    scanA_kernel<<<dim3(scan_blocks), dim3(SCAN_B), 0, stream>>>(counts, row_ptr, bsum);
    scanB_kernel<<<dim3(1), dim3(128), 0, stream>>>(bsum, scan_blocks);
    scatter_kernel<<<dim3(edge_blocks), dim3(256), 0, stream>>>(
        src0, dst0, src1, dst1, row_ptr, bsum, eidx);

    // Projections
    fuse_weights<<<dim3(768), dim3(128), 0, stream>>>(
        Wk, bk, Wm, bm, Wq, bq, Wa, ba,
        Watt0, Wmsg0, Watt1, Wmsg1, prior0, prior1, Wt, bias);
    proj_mfma<<<dim3(N_NODES / 32), dim3(256), 0, stream>>>(
        x, Wt, bias, kattC, mmsgC, qb);

    agg_kernel<<<dim3((N_NODES + 3) / 4), dim3(256), 0, stream>>>(
        (const __hip_bfloat162*)kattC, (const __hip_bfloat162*)mmsgC,
        (const __hip_bfloat162*)qb, row_ptr, counts, bsum, eidx,
        (__hip_bfloat162*)pooled);

    final_mfma<<<dim3(N_NODES / 32), dim3(256), 0, stream>>>(
        pooled, Wt, bias, x, skip, gamma, beta, out);
}